// Round 4
// baseline (96.476 us; speedup 1.0000x reference)
//
#include <hip/hip_runtime.h>
#include <hip/hip_bf16.h>

#define M_ROWS 8192
#define K_DIM 128
#define NCLS 60
#define BNT 128   // cols per tile
#define NT 8      // tiles per strip (strip = 1024 cols)

// x = q_i . q_j where q = bf16(fhat * SCL), SCL^2 = 5*log2(e)  ->  sim = x*ln2, exp(sim) = 2^x
constexpr float SCL = 2.68579007f;     // sqrt(5 * 1.4426950408889634)
constexpr float LN2 = 0.69314718056f;

using f32x4 = __attribute__((ext_vector_type(4))) float;
using s16x8 = __attribute__((ext_vector_type(8))) short;

__device__ inline float bf2f(ushort u) {
    union { unsigned int i; float f; } v; v.i = ((unsigned int)u) << 16; return v.f;
}

// ws float region: denom[8192] | S[60*128] | cntC[64]
#define NZERO (M_ROWS + NCLS * K_DIM + 64)

__global__ __launch_bounds__(256) void kinit(float* __restrict__ z, float* __restrict__ out) {
    int i = blockIdx.x * 256 + threadIdx.x;
    if (i < NZERO) z[i] = 0.f;
    if (i == 0) out[0] = 0.f;
}

// ---------------- row L2-normalize, scale, f32 -> bf16 (16 rows/block) ----------------
__global__ __launch_bounds__(256) void knorm(const float* __restrict__ feat, ushort* __restrict__ fn) {
    const int wv = threadIdx.x >> 6, lane = threadIdx.x & 63;
    int row = blockIdx.x * 16 + wv * 4;
#pragma unroll
    for (int it = 0; it < 4; ++it, ++row) {
        const float2 v = *(const float2*)&feat[(size_t)row * K_DIM + lane * 2];
        float ss = v.x * v.x + v.y * v.y;
#pragma unroll
        for (int m = 1; m < 64; m <<= 1) ss += __shfl_xor(ss, m, 64);
        const float rs = rsqrtf(ss) * SCL;
        __hip_bfloat16 ha = __float2bfloat16(v.x * rs);
        __hip_bfloat16 hb = __float2bfloat16(v.y * rs);
        ushort2 o;
        o.x = *reinterpret_cast<const ushort*>(&ha);
        o.y = *reinterpret_cast<const ushort*>(&hb);
        *(ushort2*)&fn[(size_t)row * K_DIM + lane * 2] = o;
    }
}

// ---------------- class sums: 32 blocks, LDS-private table, single fn pass ----------------
__global__ __launch_bounds__(256) void kclass(const ushort* __restrict__ fn,
                                              const int* __restrict__ labels,
                                              float* __restrict__ S, float* __restrict__ cntC) {
    __shared__ float Sl[NCLS * K_DIM];   // 30 KB
    __shared__ float Cl[NCLS];
    const int tid = threadIdx.x;
    for (int i = tid; i < NCLS * K_DIM; i += 256) Sl[i] = 0.f;
    if (tid < NCLS) Cl[tid] = 0.f;
    __syncthreads();

    const int rsub = tid >> 4;           // 16 rows concurrent
    const int kc = tid & 15;             // 16 lanes x 8 bf16 = 128 k
    const int rbase = blockIdx.x * 256;
#pragma unroll 4
    for (int it = 0; it < 16; ++it) {
        const int row = rbase + it * 16 + rsub;
        const int lab = labels[row];
        if (kc == 0) atomicAdd(&Cl[lab], 1.f);
        const s16x8 q = *(const s16x8*)&fn[(size_t)row * K_DIM + kc * 8];
        float* dst = &Sl[lab * K_DIM + kc * 8];
#pragma unroll
        for (int j = 0; j < 8; ++j) atomicAdd(&dst[j], bf2f((ushort)q[j]));
    }
    __syncthreads();
    for (int i = tid; i < NCLS * K_DIM; i += 256) atomicAdd(&S[i], Sl[i]);
    if (tid < NCLS) atomicAdd(&cntC[tid], Cl[tid]);
}

// ---------------- main: denom_i = sum_j 2^(q_i.q_j) (incl diag), full matrix ----------------
// Block: 4 waves x 32 rows = 128 rows; streams 8 tiles of 128 cols (1024-col strip).
__global__ __launch_bounds__(256) void kmain(const ushort* __restrict__ fn,
                                             float* __restrict__ denom) {
    __shared__ __align__(16) ushort ldsB[2][BNT * K_DIM];  // 2 x 32 KB double buffer
    const int tid = threadIdx.x;
    const int lane = tid & 63;
    const int lrow = lane & 15;
    const int g = lane >> 4;
    const int browW = blockIdx.x * 128 + (tid >> 6) * 32;  // this wave's first row
    const int col0 = blockIdx.y * (BNT * NT);              // strip start col

    // async stage of one 128-col tile: LDS linear dest, inverse-swizzled global source.
    // LDS[cr][c] holds global chunk (c ^ (cr&7)) of row cr (chunk = 8 bf16 = 16B)
    auto stage = [&](int buf, int t) {
        const ushort* gb = fn + (size_t)(col0 + t * BNT) * K_DIM;
#pragma unroll
        for (int it = 0; it < 8; ++it) {
            const int p = it * 256 + tid;
            const int cr = p >> 4, cc = p & 15;
            const ushort* gsrc = gb + cr * K_DIM + ((cc ^ (cr & 7)) * 8);
            ushort* ldst = &ldsB[buf][(size_t)(it * 256 + (tid & 192)) * 8];
            __builtin_amdgcn_global_load_lds((const __attribute__((address_space(1))) void*)gsrc,
                                             (__attribute__((address_space(3))) void*)ldst, 16, 0, 0);
        }
    };

    stage(0, 0);

    // persistent A fragments: rows browW..+31, K=128
    s16x8 af[2][4];
#pragma unroll
    for (int m = 0; m < 2; ++m)
#pragma unroll
        for (int kk = 0; kk < 4; ++kk)
            af[m][kk] = *(const s16x8*)&fn[(size_t)(browW + m * 16 + lrow) * K_DIM + kk * 32 + g * 8];

    float pd[2][4] = {};  // per-thread row partials over the whole strip

    for (int t = 0; t < NT; ++t) {
        __syncthreads();                  // drains stage t
        if (t < NT - 1) stage((t + 1) & 1, t + 1);
        const ushort* buf = ldsB[t & 1];
        f32x4 acc[2][8] = {};
#pragma unroll
        for (int kk = 0; kk < 4; ++kk) {
            s16x8 bfr[8];
#pragma unroll
            for (int n = 0; n < 8; ++n) {
                const int cr = n * 16 + lrow;
                const int cc = (kk * 4 + g) ^ (cr & 7);
                bfr[n] = *(const s16x8*)&buf[cr * K_DIM + cc * 8];
            }
#pragma unroll
            for (int m = 0; m < 2; ++m)
#pragma unroll
                for (int n = 0; n < 8; ++n)
                    acc[m][n] = __builtin_amdgcn_mfma_f32_16x16x32_bf16(af[m][kk], bfr[n], acc[m][n], 0, 0, 0);
        }
#pragma unroll
        for (int m = 0; m < 2; ++m)
#pragma unroll
            for (int n = 0; n < 8; ++n)
#pragma unroll
                for (int r = 0; r < 4; ++r)
                    pd[m][r] += exp2f(acc[m][n][r]);
    }

    // one reduction per row at block end: sum over the 16 column-lanes
#pragma unroll
    for (int m = 0; m < 2; ++m)
#pragma unroll
        for (int r = 0; r < 4; ++r) {
            float v = pd[m][r];
#pragma unroll
            for (int msk = 1; msk < 16; msk <<= 1) v += __shfl_xor(v, msk, 16);
            if (lrow == 0) atomicAdd(&denom[browW + m * 16 + g * 4 + r], v);
        }
}

// ---------------- finalize: per-row loss, mean ----------------
__global__ __launch_bounds__(1024) void kfin(const ushort* __restrict__ fn,
                                             const int* __restrict__ labels,
                                             const float* __restrict__ denom,
                                             const float* __restrict__ S,
                                             const float* __restrict__ cntC,
                                             float* __restrict__ out) {
    const int tid = threadIdx.x;
    const int wv = tid >> 6, lane = tid & 63;
    const int row = blockIdx.x * 16 + wv;
    const ushort2 qv = *(const ushort2*)&fn[(size_t)row * K_DIM + lane * 2];
    const float f0 = bf2f(qv.x), f1 = bf2f(qv.y);
    const int c = labels[row];
    const float2 sv = *(const float2*)&S[c * K_DIM + lane * 2];
    float dot = f0 * sv.x + f1 * sv.y;   // q_i . S_c  (includes self)
    float sii = f0 * f0 + f1 * f1;       // q_i . q_i
#pragma unroll
    for (int msk = 1; msk < 64; msk <<= 1) {
        dot += __shfl_xor(dot, msk, 64);
        sii += __shfl_xor(sii, msk, 64);
    }
    __shared__ float ls[16];
    if (lane == 0) {
        const float cf = cntC[c];                                   // count incl. self
        const float d = fmaxf(denom[row] - exp2f(sii), 1e-5f);      // exclude diagonal
        const float p = (dot - sii) * LN2;                          // matched sims, excl diag
        ls[wv] = ((cf - 1.f) * __logf(d) - p) / cf;
    }
    __syncthreads();
    if (tid == 0) {
        float s = 0.f;
#pragma unroll
        for (int i = 0; i < 16; ++i) s += ls[i];
        atomicAdd(out, s * (1.0f / M_ROWS));
    }
}

extern "C" void kernel_launch(void* const* d_in, const int* in_sizes, int n_in,
                              void* d_out, int out_size, void* d_ws, size_t ws_size,
                              hipStream_t stream) {
    (void)in_sizes; (void)n_in; (void)out_size; (void)ws_size;
    const float* feat = (const float*)d_in[0];
    const int* labels = (const int*)d_in[2];   // d_in[1] (ious) unused: coef == 1
    float* out = (float*)d_out;
    char* ws = (char*)d_ws;
    ushort* fn = (ushort*)ws;                                   // 2 MB bf16 features
    float* denom = (float*)(ws + (size_t)M_ROWS * K_DIM * 2);
    float* S = denom + M_ROWS;
    float* cntC = S + NCLS * K_DIM;

    kinit<<<(NZERO + 255) / 256, 256, 0, stream>>>(denom, out);
    knorm<<<M_ROWS / 16, 256, 0, stream>>>(feat, fn);
    kclass<<<M_ROWS / 256, 256, 0, stream>>>(fn, labels, S, cntC);
    kmain<<<dim3(M_ROWS / 128, M_ROWS / (BNT * NT)), 256, 0, stream>>>(fn, denom);
    kfin<<<M_ROWS / 16, 1024, 0, stream>>>(fn, labels, denom, S, cntC, out);
}

// Round 5
// 74.672 us; speedup vs baseline: 1.2920x; 1.2920x over previous
//
#include <hip/hip_runtime.h>
#include <hip/hip_bf16.h>

#define M_ROWS 8192
#define K_DIM 128
#define NCLS 60
#define BNT 128   // cols per tile
#define NT 8      // tiles per strip (strip = 1024 cols)
#define NSLAB 128 // kclass partial tables

// x = q_i . q_j where q = bf16(fhat * SCL), SCL^2 = 5*log2(e)  ->  sim = x*ln2, exp(sim) = 2^x
constexpr float SCL = 2.68579007f;     // sqrt(5 * 1.4426950408889634)
constexpr float LN2 = 0.69314718056f;

using f32x4 = __attribute__((ext_vector_type(4))) float;
using s16x8 = __attribute__((ext_vector_type(8))) short;

__device__ inline float bf2f(ushort u) {
    union { unsigned int i; float f; } v; v.i = ((unsigned int)u) << 16; return v.f;
}

__global__ __launch_bounds__(256) void kinit(float* __restrict__ denom, float* __restrict__ out) {
    int i = blockIdx.x * 256 + threadIdx.x;
    if (i < M_ROWS) denom[i] = 0.f;
    if (i == 0) out[0] = 0.f;
}

// ---------------- row L2-normalize, scale, f32 -> bf16 (16 rows/block) ----------------
__global__ __launch_bounds__(256) void knorm(const float* __restrict__ feat, ushort* __restrict__ fn) {
    const int wv = threadIdx.x >> 6, lane = threadIdx.x & 63;
    int row = blockIdx.x * 16 + wv * 4;
#pragma unroll
    for (int it = 0; it < 4; ++it, ++row) {
        const float2 v = *(const float2*)&feat[(size_t)row * K_DIM + lane * 2];
        float ss = v.x * v.x + v.y * v.y;
#pragma unroll
        for (int m = 1; m < 64; m <<= 1) ss += __shfl_xor(ss, m, 64);
        const float rs = rsqrtf(ss) * SCL;
        __hip_bfloat16 ha = __float2bfloat16(v.x * rs);
        __hip_bfloat16 hb = __float2bfloat16(v.y * rs);
        ushort2 o;
        o.x = *reinterpret_cast<const ushort*>(&ha);
        o.y = *reinterpret_cast<const ushort*>(&hb);
        *(ushort2*)&fn[(size_t)row * K_DIM + lane * 2] = o;
    }
}

// ---------------- class partials: 128 blocks x 64 rows, LDS table -> slab ----------------
__global__ __launch_bounds__(256) void kclassp(const ushort* __restrict__ fn,
                                               const int* __restrict__ labels,
                                               float* __restrict__ slabS,
                                               float* __restrict__ slabC) {
    __shared__ float Sl[NCLS * K_DIM];   // 30 KB
    __shared__ float Cl[NCLS];
    __shared__ int lab[64];
    const int tid = threadIdx.x;
    const int rbase = blockIdx.x * 64;
    for (int i = tid; i < NCLS * K_DIM; i += 256) Sl[i] = 0.f;
    if (tid < NCLS) Cl[tid] = 0.f;
    if (tid < 64) lab[tid] = labels[rbase + tid];
    __syncthreads();

    const int rsub = tid >> 4;           // 16 rows concurrent
    const int kc = tid & 15;             // 16 lanes x 8 bf16 = 128 k
#pragma unroll
    for (int it = 0; it < 4; ++it) {
        const int r = it * 16 + rsub;
        const int lb = lab[r];
        if (kc == 0) atomicAdd(&Cl[lb], 1.f);
        const s16x8 q = *(const s16x8*)&fn[(size_t)(rbase + r) * K_DIM + kc * 8];
        float* dst = &Sl[lb * K_DIM + kc * 8];
#pragma unroll
        for (int j = 0; j < 8; ++j) atomicAdd(&dst[j], bf2f((ushort)q[j]));
    }
    __syncthreads();
    float* oS = slabS + (size_t)blockIdx.x * (NCLS * K_DIM);
    for (int i = tid; i < NCLS * K_DIM; i += 256) oS[i] = Sl[i];
    if (tid < NCLS) slabC[blockIdx.x * 64 + tid] = Cl[tid];
}

// ---------------- reduce slabs -> S, cntC (plain writes, no init needed) ----------------
__global__ __launch_bounds__(256) void kreduce(const float* __restrict__ slabS,
                                               const float* __restrict__ slabC,
                                               float* __restrict__ S,
                                               float* __restrict__ cntC) {
    const int i = blockIdx.x * 256 + threadIdx.x;
    if (i < NCLS * K_DIM) {
        float s = 0.f;
        for (int b = 0; b < NSLAB; ++b) s += slabS[(size_t)b * (NCLS * K_DIM) + i];
        S[i] = s;
    } else if (i < NCLS * K_DIM + NCLS) {
        const int c = i - NCLS * K_DIM;
        float s = 0.f;
        for (int b = 0; b < NSLAB; ++b) s += slabC[b * 64 + c];
        cntC[c] = s;
    }
}

// ---------------- main: denom_i = sum_j 2^(q_i.q_j) (incl diag) ----------------
// Block: 128 rows x 128-col tiles, 4 waves in 2x2 quadrants of 64x64 each;
// streams NT=8 tiles (1024-col strip) through a double-buffered LDS.
__global__ __launch_bounds__(256) void kmain(const ushort* __restrict__ fn,
                                             float* __restrict__ denom) {
    __shared__ __align__(16) ushort ldsB[2][BNT * K_DIM];  // 2 x 32 KB
    const int tid = threadIdx.x;
    const int lane = tid & 63;
    const int lrow = lane & 15;
    const int g = lane >> 4;
    const int wv = tid >> 6;
    const int wr = (wv >> 1) * 64;   // quadrant row offset
    const int wc = (wv & 1) * 64;    // quadrant col offset
    const int brow = blockIdx.x * 128;
    const int col0 = blockIdx.y * (BNT * NT);

    // async stage of one 128-col tile: LDS linear dest, inverse-swizzled global source.
    // LDS[cr][c] holds global chunk (c ^ (cr&7)) of row cr (chunk = 8 bf16 = 16B)
    auto stage = [&](int buf, int t) {
        const ushort* gb = fn + (size_t)(col0 + t * BNT) * K_DIM;
#pragma unroll
        for (int it = 0; it < 8; ++it) {
            const int p = it * 256 + tid;
            const int cr = p >> 4, cc = p & 15;
            const ushort* gsrc = gb + cr * K_DIM + ((cc ^ (cr & 7)) * 8);
            ushort* ldst = &ldsB[buf][(size_t)(it * 256 + (tid & 192)) * 8];
            __builtin_amdgcn_global_load_lds((const __attribute__((address_space(1))) void*)gsrc,
                                             (__attribute__((address_space(3))) void*)ldst, 16, 0, 0);
        }
    };

    stage(0, 0);

    // persistent A fragments: rows brow+wr .. +63, K=128
    s16x8 af[4][4];
#pragma unroll
    for (int m = 0; m < 4; ++m)
#pragma unroll
        for (int kk = 0; kk < 4; ++kk)
            af[m][kk] = *(const s16x8*)&fn[(size_t)(brow + wr + m * 16 + lrow) * K_DIM + kk * 32 + g * 8];

    float pd[4][4] = {};  // per-thread row partials over the strip

    for (int t = 0; t < NT; ++t) {
        __syncthreads();                  // drains stage t
        if (t < NT - 1) stage((t + 1) & 1, t + 1);
        const ushort* buf = ldsB[t & 1];
        f32x4 acc[4][4] = {};
#pragma unroll
        for (int kk = 0; kk < 4; ++kk) {
            s16x8 bfr[4];
#pragma unroll
            for (int n = 0; n < 4; ++n) {
                const int cr = wc + n * 16 + lrow;
                const int cc = (kk * 4 + g) ^ (cr & 7);
                bfr[n] = *(const s16x8*)&buf[cr * K_DIM + cc * 8];
            }
#pragma unroll
            for (int m = 0; m < 4; ++m)
#pragma unroll
                for (int n = 0; n < 4; ++n)
                    acc[m][n] = __builtin_amdgcn_mfma_f32_16x16x32_bf16(af[m][kk], bfr[n], acc[m][n], 0, 0, 0);
        }
#pragma unroll
        for (int m = 0; m < 4; ++m)
#pragma unroll
            for (int n = 0; n < 4; ++n)
#pragma unroll
                for (int r = 0; r < 4; ++r)
                    pd[m][r] += exp2f(acc[m][n][r]);
    }

    // row partials: reduce across 16 column-lanes; 2 waves (wc=0,64) add per row
#pragma unroll
    for (int m = 0; m < 4; ++m)
#pragma unroll
        for (int r = 0; r < 4; ++r) {
            float v = pd[m][r];
#pragma unroll
            for (int msk = 1; msk < 16; msk <<= 1) v += __shfl_xor(v, msk, 16);
            if (lrow == 0) atomicAdd(&denom[brow + wr + m * 16 + g * 4 + r], v);
        }
}

// ---------------- finalize: per-row loss, mean ----------------
__global__ __launch_bounds__(1024) void kfin(const ushort* __restrict__ fn,
                                             const int* __restrict__ labels,
                                             const float* __restrict__ denom,
                                             const float* __restrict__ S,
                                             const float* __restrict__ cntC,
                                             float* __restrict__ out) {
    const int tid = threadIdx.x;
    const int wv = tid >> 6, lane = tid & 63;
    const int row = blockIdx.x * 16 + wv;
    const ushort2 qv = *(const ushort2*)&fn[(size_t)row * K_DIM + lane * 2];
    const float f0 = bf2f(qv.x), f1 = bf2f(qv.y);
    const int c = labels[row];
    const float2 sv = *(const float2*)&S[c * K_DIM + lane * 2];
    float dot = f0 * sv.x + f1 * sv.y;   // q_i . S_c  (includes self)
    float sii = f0 * f0 + f1 * f1;       // q_i . q_i
#pragma unroll
    for (int msk = 1; msk < 64; msk <<= 1) {
        dot += __shfl_xor(dot, msk, 64);
        sii += __shfl_xor(sii, msk, 64);
    }
    __shared__ float ls[16];
    if (lane == 0) {
        const float cf = cntC[c];                                   // count incl. self
        const float d = fmaxf(denom[row] - exp2f(sii), 1e-5f);      // exclude diagonal
        const float p = (dot - sii) * LN2;                          // matched sims, excl diag
        ls[wv] = ((cf - 1.f) * __logf(d) - p) / cf;
    }
    __syncthreads();
    if (tid == 0) {
        float s = 0.f;
#pragma unroll
        for (int i = 0; i < 16; ++i) s += ls[i];
        atomicAdd(out, s * (1.0f / M_ROWS));
    }
}

extern "C" void kernel_launch(void* const* d_in, const int* in_sizes, int n_in,
                              void* d_out, int out_size, void* d_ws, size_t ws_size,
                              hipStream_t stream) {
    (void)in_sizes; (void)n_in; (void)out_size; (void)ws_size;
    const float* feat = (const float*)d_in[0];
    const int* labels = (const int*)d_in[2];   // d_in[1] (ious) unused: coef == 1
    float* out = (float*)d_out;
    char* ws = (char*)d_ws;
    ushort* fn = (ushort*)ws;                                   // 2 MB bf16 features
    float* denom = (float*)(ws + (size_t)M_ROWS * K_DIM * 2);   // 32 KB
    float* S = denom + M_ROWS;                                  // 30 KB
    float* cntC = S + NCLS * K_DIM;                             // 256 B
    float* slabS = cntC + 64;                                   // 128 x 30 KB
    float* slabC = slabS + (size_t)NSLAB * NCLS * K_DIM;        // 128 x 256 B

    kinit<<<(M_ROWS + 255) / 256, 256, 0, stream>>>(denom, out);
    knorm<<<M_ROWS / 16, 256, 0, stream>>>(feat, fn);
    kclassp<<<NSLAB, 256, 0, stream>>>(fn, labels, slabS, slabC);
    kreduce<<<31, 256, 0, stream>>>(slabS, slabC, S, cntC);
    kmain<<<dim3(M_ROWS / 128, M_ROWS / (BNT * NT)), 256, 0, stream>>>(fn, denom);
    kfin<<<M_ROWS / 16, 1024, 0, stream>>>(fn, labels, denom, S, cntC, out);
}